// Round 4
// baseline (13565.778 us; speedup 1.0000x reference)
//
#include <hip/hip_runtime.h>
#include <cstdint>
#include <cstddef>

// Reverse LSTM, B=128, T=2048, H=512, input dim 1.
// 256 WGs = 8 batch-groups (16 batches) x 32 column-parts (16 hidden units x 4 gates).
// Wh slice persistent in LDS (dual-bf16 hi/lo, 3-MFMA ~f32-accurate product).
// Cross-WG h exchange: TAG-IN-PAYLOAD 8B atomic words (tag<<32 | dualbf16),
// depth-2 buffer by step parity. The consumer poll IS the data load: no flags,
// no fences, no producer-side vmcnt drain. Raw lgkmcnt+s_barrier (no vmcnt)
// keeps publish/out stores fire-and-forget.
// Safety: WG publishes h(t+1) only after BAR1(t+1) <= all 4 waves saw all 32
// producers at tag t <= (data dep) all reads of h(t-1) complete => depth-2 WAR
// safe. Tags at parity (t-1)&1 are {t-3, t-1, poison}; equality-wait is exact;
// 0xAA poison never matches (tags <= 2047) so no ws initialization is needed.

#define TSEQ 2048
#define HID  512
#define NGRP 8
#define MB   16      // batches per group
#define PPART 32     // WGs per group (column parts)
#define SH   16      // hidden units per WG
#define NCOL 64      // 4 gates * SH
#define WSTR 520     // padded k-stride (bf16 elems) for conflict-free ds_read_b128
#define ZSTR 65      // padded zbuf col stride (dwords)

typedef float f32x4 __attribute__((ext_vector_type(4)));
typedef short bf16x8 __attribute__((ext_vector_type(8)));

__device__ __forceinline__ unsigned short f2bf(float f) {
  uint32_t u = __float_as_uint(f);
  u += 0x7fffu + ((u >> 16) & 1u);   // RNE
  return (unsigned short)(u >> 16);
}
__device__ __forceinline__ float bf2f(unsigned short b) {
  return __uint_as_float(((uint32_t)b) << 16);
}
__device__ __forceinline__ float sigm(float z) {
  return 1.0f / (1.0f + __expf(-z));
}
__device__ __forceinline__ float tanh_f(float z) {
  float a = fabsf(z);
  float e = __expf(-2.0f * a);
  float t = (1.0f - e) / (1.0f + e);
  return copysignf(t, z);
}

extern "C" __global__ void __launch_bounds__(256, 1)
lstm_rev_kernel(const float* __restrict__ x, const float* __restrict__ Wi,
                const float* __restrict__ Wh, const float* __restrict__ bias,
                float* __restrict__ out, unsigned long long* __restrict__ hexq)
{
  extern __shared__ char smem[];
  unsigned short* wh_hi = (unsigned short*)smem;           // [NCOL][WSTR] bf16 hi
  unsigned short* wh_lo = wh_hi + NCOL * WSTR;             // [NCOL][WSTR] bf16 lo
  float* zbuf = (float*)(wh_lo + NCOL * WSTR);             // [4][MB][ZSTR] partial z
  float* wi_l = zbuf + 4 * MB * ZSTR;                      // [NCOL]
  float* bi_l = wi_l + NCOL;                               // [NCOL]

  const int tid = threadIdx.x;
  const int bid = blockIdx.x;
  const int g = bid >> 5;        // batch group 0..7
  const int p = bid & 31;        // column part 0..31

  // ---- one-time: stage Wi/bias and the dual-bf16 Wh slice into LDS ----
  for (int c = tid; c < NCOL; c += 256) {
    int G = c >> 4, u = c & 15;
    int j = G * HID + p * SH + u;
    wi_l[c] = Wi[j];
    bi_l[c] = bias[j];
  }
  for (int idx = tid; idx < NCOL * HID; idx += 256) {
    int col = idx & (NCOL - 1);            // consecutive tid -> consecutive col (coalesced)
    int k   = idx >> 6;
    int G = col >> 4, u = col & 15;
    float v = Wh[(size_t)k * (4 * HID) + G * HID + p * SH + u];
    unsigned short hi = f2bf(v);
    unsigned short lo = f2bf(v - bf2f(hi));
    wh_hi[col * WSTR + k] = hi;
    wh_lo[col * WSTR + k] = lo;
  }
  __syncthreads();

  const int lane = tid & 63;
  const int wave = tid >> 6;     // MFMA k-split: wave w owns k in [w*128, w*128+128)
  const int arow = lane & 15;    // A row (batch) / D col
  const int kgrp = lane >> 4;    // 0..3
  const int gb = tid >> 4;       // gate-phase batch 0..15
  const int gu = tid & 15;       // gate-phase hidden unit 0..15

  float wiv[4], biv[4];
  #pragma unroll
  for (int G = 0; G < 4; ++G) { wiv[G] = wi_l[G * 16 + gu]; biv[G] = bi_l[G * 16 + gu]; }

  // hexq: [2][NGRP][MB][HID] u64 = (tag<<32)|(bf16hi<<16|bf16lo).  1 MiB in ws.
  // consumer base (this lane's k-slice of batch 'arow'), per parity:
  const size_t cb0 = ((size_t)(0 * NGRP + g) * MB + arow) * HID + wave * 128 + kgrp * 8;
  const size_t cb1 = ((size_t)(1 * NGRP + g) * MB + arow) * HID + wave * 128 + kgrp * 8;
  // producer slot (this thread's (batch gb, unit p*SH+gu)), per parity:
  const size_t pw0 = ((size_t)(0 * NGRP + g) * MB + gb) * HID + p * SH + gu;
  const size_t pw1 = ((size_t)(1 * NGRP + g) * MB + gb) * HID + p * SH + gu;

  float cst = 0.0f;              // persistent c state for (gb, p*SH+gu)
  const float* xrow = x + (size_t)(g * MB + gb) * TSEQ;
  float* orow = out + (size_t)(g * MB + gb) * TSEQ * HID + p * SH + gu;

  for (int t = 0; t < TSEQ; ++t) {
    float xv = xrow[TSEQ - 1 - t];            // independent of h: issue before the poll
    float xwb[4];
    #pragma unroll
    for (int G = 0; G < 4; ++G) xwb[G] = fmaf(xv, wiv[G], biv[G]);

    if (t > 0) {
      const uint32_t need = (uint32_t)(t - 1);
      const unsigned long long* pb = hexq + (((t - 1) & 1) ? cb1 : cb0);
      f32x4 acc[4] = {{0,0,0,0},{0,0,0,0},{0,0,0,0},{0,0,0,0}};
      #pragma unroll
      for (int cc = 0; cc < 4; ++cc) {
        // ---- poll = data load: spin until this lane's 8 words carry tag t-1 ----
        unsigned long long W[8];
        while (true) {
          bool ok = true;
          #pragma unroll
          for (int j = 0; j < 8; ++j) {
            W[j] = __hip_atomic_load(pb + cc * 32 + j,
                                     __ATOMIC_RELAXED, __HIP_MEMORY_SCOPE_AGENT);
            ok = ok && ((uint32_t)(W[j] >> 32) == need);
          }
          if (__all((int)ok)) break;
        }
        bf16x8 ahi, alo;
        #pragma unroll
        for (int e = 0; e < 8; ++e) {
          uint32_t pl = (uint32_t)W[e];
          ahi[e] = (short)(pl >> 16);
          alo[e] = (short)(pl & 0xffffu);
        }
        const int kb = wave * 128 + kgrp * 8 + cc * 32;
        #pragma unroll
        for (int n = 0; n < 4; ++n) {
          const int col = n * 16 + arow;
          bf16x8 bhi = *(const bf16x8*)(wh_hi + col * WSTR + kb);
          bf16x8 blo = *(const bf16x8*)(wh_lo + col * WSTR + kb);
          acc[n] = __builtin_amdgcn_mfma_f32_16x16x32_bf16(ahi, bhi, acc[n], 0, 0, 0);
          acc[n] = __builtin_amdgcn_mfma_f32_16x16x32_bf16(ahi, blo, acc[n], 0, 0, 0);
          acc[n] = __builtin_amdgcn_mfma_f32_16x16x32_bf16(alo, bhi, acc[n], 0, 0, 0);
        }
      }
      // spill partial z: D layout col=lane&15, row=(lane>>4)*4+reg  [m89-verified]
      #pragma unroll
      for (int n = 0; n < 4; ++n) {
        #pragma unroll
        for (int j = 0; j < 4; ++j) {
          int row = kgrp * 4 + j;
          zbuf[(wave * MB + row) * ZSTR + n * 16 + arow] = acc[n][j];
        }
      }
    }
    // BAR1: zbuf(t) complete. Raw lgkm-only barrier: no vmcnt drain.
    asm volatile("s_waitcnt lgkmcnt(0)\n\ts_barrier" ::: "memory");

    // ---- gate phase: one thread per (batch, hidden unit) ----
    float z[4];
    #pragma unroll
    for (int G = 0; G < 4; ++G) {
      float s = xwb[G];
      if (t > 0) {
        #pragma unroll
        for (int w = 0; w < 4; ++w) s += zbuf[(w * MB + gb) * ZSTR + G * 16 + gu];
      }
      z[G] = s;
    }
    float ig = sigm(z[0]);
    float fg = sigm(z[1]);
    float gg = tanh_f(z[2]);
    float og = sigm(z[3]);
    cst = fg * cst + ig * gg;
    float h = og * tanh_f(cst);

    // publish h: single 8B atomic word (tag | dual-bf16), fire-and-forget
    unsigned short hh = f2bf(h);
    unsigned short hl = f2bf(h - bf2f(hh));
    unsigned long long word = ((unsigned long long)(uint32_t)t << 32)
                            | (unsigned long long)(((uint32_t)hh << 16) | (uint32_t)hl);
    __hip_atomic_store(hexq + ((t & 1) ? pw1 : pw0), word,
                       __ATOMIC_RELAXED, __HIP_MEMORY_SCOPE_AGENT);

    // BAR2: zbuf reads done before next step's spill (WAR). lgkm-only again.
    asm volatile("s_waitcnt lgkmcnt(0)\n\ts_barrier" ::: "memory");

    // out store last: HBM ack drains under the next step's poll/MFMA
    __builtin_nontemporal_store(h, &orow[(size_t)t * HID]);
  }
}

extern "C" void kernel_launch(void* const* d_in, const int* in_sizes, int n_in,
                              void* d_out, int out_size, void* d_ws, size_t ws_size,
                              hipStream_t stream) {
  // inputs: 0=s (unused), 1=x (128x2048 f32), 2=Wi (2048), 3=Wh (512x2048), 4=b (2048)
  const float* x  = (const float*)d_in[1];
  const float* Wi = (const float*)d_in[2];
  const float* Wh = (const float*)d_in[3];
  const float* bs = (const float*)d_in[4];
  float* out = (float*)d_out;
  unsigned long long* hexq = (unsigned long long*)d_ws;   // 2*8*16*512*8B = 1 MiB

  const size_t SMEM = (size_t)(2 * NCOL * WSTR) * sizeof(unsigned short)
                    + (size_t)(4 * MB * ZSTR) * sizeof(float)
                    + (size_t)(2 * NCOL) * sizeof(float);   // 150,272 B

  hipFuncSetAttribute(reinterpret_cast<const void*>(lstm_rev_kernel),
                      hipFuncAttributeMaxDynamicSharedMemorySize, (int)SMEM);
  // No ws initialization needed: 0xAA poison tags (0xAAAAAAAA) never equal a
  // real tag (0..2047), and the equality-wait protocol reads nothing at t=0.

  void* args[] = { (void*)&x, (void*)&Wi, (void*)&Wh, (void*)&bs, (void*)&out, (void*)&hexq };
  hipLaunchCooperativeKernel(reinterpret_cast<const void*>(lstm_rev_kernel),
                             dim3(256), dim3(256), args, (unsigned)SMEM, stream);
}